// Round 20
// baseline (175.359 us; speedup 1.0000x reference)
//
#include <hip/hip_runtime.h>
#include <cstdint>
#include <cstddef>

typedef _Float16 h16;
typedef __attribute__((ext_vector_type(8))) _Float16 half8;
typedef __attribute__((ext_vector_type(4))) _Float16 half4;
typedef __attribute__((ext_vector_type(2))) _Float16 half2v;
typedef __attribute__((ext_vector_type(4))) float f32x4;
typedef __attribute__((ext_vector_type(2))) float f32x2;

#define NB 16384
#define NTAB 26
#define NR 100000

__device__ __forceinline__ void gload16(const void* g, void* l) {
  __builtin_amdgcn_global_load_lds(
      (const __attribute__((address_space(1))) unsigned int*)g,
      (__attribute__((address_space(3))) unsigned int*)l, 16, 0, 0);
}

// ---- f32 -> fp16 weight conversion (7 segments, one launch).
__global__ __launch_bounds__(256) void cvt_all_k(
    const float* __restrict__ s0, const float* __restrict__ s1,
    const float* __restrict__ s2, const float* __restrict__ s3,
    const float* __restrict__ s4, const float* __restrict__ s5,
    const float* __restrict__ s6, h16* __restrict__ dst) {
  int b = blockIdx.x;
  const float* src; int K, kl, i0; size_t doff;
  if (b < 512)       { src=s0; K=512;  kl=9;  i0=(b-0)*256;    doff=0; }
  else if (b < 640)  { src=s1; K=256;  kl=8;  i0=(b-512)*256;  doff=131072; }
  else if (b < 2688) { src=s2; K=479;  kl=9;  i0=(b-640)*256;  doff=163840; }
  else if (b < 6784) { src=s3; K=1024; kl=10; i0=(b-2688)*256; doff=688128; }
  else if (b < 8832) { src=s4; K=1024; kl=10; i0=(b-6784)*256; doff=1736704; }
  else if (b < 9344) { src=s5; K=512;  kl=9;  i0=(b-8832)*256; doff=2260992; }
  else               { src=s6; K=13;   kl=5;  i0=(b-9344)*256; doff=2392064; }
  int i = i0 + threadIdx.x;
  int n = i >> kl, k = i & ((1 << kl) - 1);
  dst[doff + i] = (k < K) ? (h16)src[(size_t)n * K + k] : (h16)0.f;
}

// ---- fully fused bottom stack (R19).
__global__ __launch_bounds__(256, 2) void mid_k(
    const float* __restrict__ x, const h16* __restrict__ W0p,
    const float* __restrict__ b0, const h16* __restrict__ W1,
    const float* __restrict__ b1, const h16* __restrict__ W2,
    const float* __restrict__ b2, h16* __restrict__ Xc) {
  __shared__ __align__(16) h16 Y0s[32 * 520];
  __shared__ __align__(16) h16 Sb[256 * 64];
  __shared__ __align__(16) h16 xs16[32 * 32];
  h16* Y1 = Y0s;
  const int tid = threadIdx.x;
  const int lane = tid & 63;
  const int w = tid >> 6;
  const int l15 = lane & 15;
  const int kq = lane >> 4;
  const int l7 = lane & 7;
  const size_t row0 = (size_t)blockIdx.x * 32;

  for (int i = tid; i < 32 * 32; i += 256) xs16[i] = (h16)0.f;
  __syncthreads();
  for (int i = tid; i < 32 * 13; i += 256) {
    int r = i / 13, k = i - r * 13;
    xs16[r * 32 + k] = (h16)x[(row0 + r) * 13 + k];
  }
  __syncthreads();
#pragma unroll
  for (int mi = 0; mi < 2; ++mi) {
    half8 xf = *(const half8*)&xs16[(mi * 16 + l15) * 32 + kq * 8];
#pragma unroll
    for (int ni = 0; ni < 8; ++ni) {
      const int c = w * 128 + ni * 16 + l15;
      half8 wf = *(const half8*)&W0p[c * 32 + kq * 8];
      f32x4 a0 = {};
      a0 = __builtin_amdgcn_mfma_f32_16x16x32_f16(wf, xf, a0, 0, 0, 0);
      const int colb = w * 128 + ni * 16 + kq * 4;
      const f32x4 bv = *(const f32x4*)&b0[colb];
      half4 h;
#pragma unroll
      for (int ri = 0; ri < 4; ++ri)
        h[ri] = (h16)fmaxf(a0[ri] + bv[ri], 0.f);
      *(half4*)&Y0s[(mi * 16 + l15) * 520 + colb] = h;
    }
  }
  __syncthreads();

  const int srow = tid >> 3;
  const int sch = (tid & 7) ^ (srow & 7);
  const h16* gB = W1 + (size_t)srow * 512 + sch * 8;

  f32x4 acc[2][4] = {};
  for (int t = 0; t < 8; ++t) {
    const int k0 = t * 64;
#pragma unroll
    for (int i = 0; i < 8; ++i)
      gload16(gB + (size_t)(i * 32) * 512 + k0, Sb + i * 2048 + tid * 8);
    __syncthreads();
#pragma unroll
    for (int kk = 0; kk < 2; ++kk) {
      const int kb = kk * 4 + kq;
      const int sl = (kb ^ l7) << 3;
      half8 a[2], bfr[4];
#pragma unroll
      for (int mi = 0; mi < 2; ++mi)
        a[mi] = *(const half8*)&Y0s[(mi * 16 + l15) * 520 + k0 + kb * 8];
#pragma unroll
      for (int ni = 0; ni < 4; ++ni)
        bfr[ni] = *(const half8*)&Sb[(w * 64 + ni * 16 + l15) * 64 + sl];
#pragma unroll
      for (int mi = 0; mi < 2; ++mi)
#pragma unroll
        for (int ni = 0; ni < 4; ++ni)
          acc[mi][ni] = __builtin_amdgcn_mfma_f32_16x16x32_f16(bfr[ni], a[mi], acc[mi][ni], 0, 0, 0);
    }
    __syncthreads();
  }

#pragma unroll
  for (int mi = 0; mi < 2; ++mi) {
    const int row = mi * 16 + l15;
#pragma unroll
    for (int ni = 0; ni < 4; ++ni) {
      const int col = w * 64 + ni * 16 + kq * 4;
      const f32x4 bv = *(const f32x4*)&b1[col];
      half4 h;
#pragma unroll
      for (int ri = 0; ri < 4; ++ri)
        h[ri] = (h16)fmaxf(acc[mi][ni][ri] + bv[ri], 0.f);
      *(half4*)&Y1[row * 264 + col] = h;
    }
  }
  __syncthreads();

  f32x4 acc2[2][2] = {};
  for (int ks = 0; ks < 8; ++ks) {
    half8 av[2], bv[2];
#pragma unroll
    for (int mi = 0; mi < 2; ++mi)
      av[mi] = *(const half8*)&Y1[(mi * 16 + l15) * 264 + ks * 32 + kq * 8];
#pragma unroll
    for (int nf = 0; nf < 2; ++nf) {
      const int col = (w * 2 + nf) * 16 + l15;
      bv[nf] = *(const half8*)&W2[(size_t)col * 256 + ks * 32 + kq * 8];
    }
#pragma unroll
    for (int mi = 0; mi < 2; ++mi)
#pragma unroll
      for (int nf = 0; nf < 2; ++nf)
        acc2[mi][nf] = __builtin_amdgcn_mfma_f32_16x16x32_f16(bv[nf], av[mi], acc2[mi][nf], 0, 0, 0);
  }
#pragma unroll
  for (int mi = 0; mi < 2; ++mi) {
    const size_t row = row0 + mi * 16 + l15;
#pragma unroll
    for (int nf = 0; nf < 2; ++nf) {
      const int col = (w * 2 + nf) * 16 + kq * 4;
      const f32x4 bv = *(const f32x4*)&b2[col];
      half4 h;
#pragma unroll
      for (int ri = 0; ri < 4; ++ri)
        h[ri] = (h16)fmaxf(acc2[mi][nf][ri] + bv[ri], 0.f);
      *(half4*)&Xc[row * 128 + col] = h;
    }
  }
}

// ---- 128x128-tile single-buffered fp16 MFMA GEMM (R15 best): T0.
template <int GYL>
__global__ __launch_bounds__(256, 4) void gemm_sb(
    const h16* __restrict__ A, const h16* __restrict__ W,
    const float* __restrict__ bias, h16* __restrict__ C, int N, int K) {
  __shared__ __align__(16) h16 As[128 * 64];
  __shared__ __align__(16) h16 Bs[128 * 64];
  const int b = blockIdx.x;
  const int c8 = b & 7;
  const int q = b >> 3;
  const int jcol = q & ((1 << GYL) - 1);
  const int krow = ((q >> GYL) << 3) | c8;
  const int tid = threadIdx.x;
  const int lane = tid & 63;
  const int wave = tid >> 6;
  const int wm = wave >> 1, wn = wave & 1;
  const size_t row0 = (size_t)krow * 128;
  const size_t col0 = (size_t)jcol * 128;
  const int lr = lane >> 3;
  const int swzc = (((lane & 7) ^ lr) << 3);
  const int l15 = lane & 15;
  const int kq = lane >> 4;
  const int l7 = lane & 7;
  const int nt = K >> 6;

  const h16* ga = A + (row0 + wave * 32 + lr) * (size_t)K + swzc;
  const h16* gb = W + (col0 + wave * 32 + lr) * (size_t)K + swzc;

  f32x4 acc[4][4] = {};

  for (int t = 0; t < nt; ++t) {
    const int k0 = t << 6;
    h16* la = As + wave * 2048;
    h16* lb = Bs + wave * 2048;
#pragma unroll
    for (int i = 0; i < 4; ++i) {
      gload16(ga + (size_t)i * 8 * K + k0, la + i * 512);
      gload16(gb + (size_t)i * 8 * K + k0, lb + i * 512);
    }
    __syncthreads();
#pragma unroll
    for (int kk = 0; kk < 2; ++kk) {
      half8 a[4], bfr[4];
      const int kb = kk * 4 + kq;
#pragma unroll
      for (int mi = 0; mi < 4; ++mi)
        a[mi] = *(const half8*)&As[(wm * 64 + mi * 16 + l15) * 64 + ((kb ^ l7) << 3)];
#pragma unroll
      for (int ni = 0; ni < 4; ++ni)
        bfr[ni] = *(const half8*)&Bs[(wn * 64 + ni * 16 + l15) * 64 + ((kb ^ l7) << 3)];
#pragma unroll
      for (int mi = 0; mi < 4; ++mi)
#pragma unroll
        for (int ni = 0; ni < 4; ++ni)
          acc[mi][ni] = __builtin_amdgcn_mfma_f32_16x16x32_f16(a[mi], bfr[ni], acc[mi][ni], 0, 0, 0);
    }
    __syncthreads();
  }

#pragma unroll
  for (int mi = 0; mi < 4; ++mi)
#pragma unroll
    for (int ni = 0; ni < 4; ++ni) {
      const size_t col = col0 + wn * 64 + ni * 16 + l15;
      const float bv = bias[col];
#pragma unroll
      for (int ri = 0; ri < 4; ++ri) {
        const size_t row = row0 + wm * 64 + mi * 16 + kq * 4 + ri;
        float v = acc[mi][ni][ri] + bv;
        C[row * N + col] = (h16)fmaxf(v, 0.f);
      }
    }
}

// ---- NEW for T1: 128x128-tile DOUBLE-buffered BK=32 counted-vmcnt GEMM
// at 4 blocks/CU (the untried quadrant: dbuf latency-hiding AND cross-block
// TLP; 2x16KB x2 = 32KB LDS). Per K-tile: 4 gloads/thread, wait vmcnt(4)
// (next tile's loads stay in flight), 2 raw barriers; wrap prefetch.
// BK=32 layout (64B rows): read slot = kq ^ (row&3) -> exactly 8 lanes per
// bank-quad (b128 minimum). Staging inverse on the global source:
// c = (t&3) ^ ((t>>2)&3), linear global_load_lds dest (both-sides rule).
template <int GYL>
__global__ __launch_bounds__(256, 4) void gemm_db32(
    const h16* __restrict__ A, const h16* __restrict__ W,
    const float* __restrict__ bias, h16* __restrict__ C, int N, int K) {
  __shared__ __align__(16) h16 As[2][128 * 32];
  __shared__ __align__(16) h16 Bs[2][128 * 32];
  const int b = blockIdx.x;
  const int c8 = b & 7;
  const int q = b >> 3;
  const int jcol = q & ((1 << GYL) - 1);
  const int krow = ((q >> GYL) << 3) | c8;
  const int tid = threadIdx.x;
  const int lane = tid & 63;
  const int wave = tid >> 6;
  const int wm = wave >> 1, wn = wave & 1;
  const size_t row0 = (size_t)krow * 128;
  const size_t col0 = (size_t)jcol * 128;
  const int l15 = lane & 15;
  const int kq = lane >> 4;
  const int nt = K >> 5;

  // staging: thread t fills LDS h16 offset t*8 of each 4KB segment
  // -> row = (t>>2) + i*64, logical chunk c = (t&3) ^ ((t>>2)&3)
  const int srow = tid >> 2;                       // 0..63
  const int sch = (tid & 3) ^ (srow & 3);          // inverse of read swizzle
  const h16* ga = A + (row0 + srow) * (size_t)K + sch * 8;
  const h16* gb = W + (col0 + srow) * (size_t)K + sch * 8;

  f32x4 acc[4][4] = {};

  auto stage = [&](int buf, int kt) {
    if (kt >= nt) kt -= nt;
    const int k0 = kt << 5;
#pragma unroll
    for (int i = 0; i < 2; ++i) {
      gload16(ga + (size_t)(i * 64) * K + k0, &As[buf][i * 2048 + tid * 8]);
      gload16(gb + (size_t)(i * 64) * K + k0, &Bs[buf][i * 2048 + tid * 8]);
    }
  };

  stage(0, 0);
  for (int t = 0; t < nt; ++t) {
    const int p = t & 1;
    stage(p ^ 1, t + 1);
    asm volatile("s_waitcnt vmcnt(4)" ::: "memory");
    __builtin_amdgcn_s_barrier();
    __builtin_amdgcn_sched_barrier(0);
    half8 a[4], bfr[4];
#pragma unroll
    for (int mi = 0; mi < 4; ++mi) {
      const int r = wm * 64 + mi * 16 + l15;
      a[mi] = *(const half8*)&As[p][r * 32 + ((kq ^ (r & 3)) << 3)];
    }
#pragma unroll
    for (int ni = 0; ni < 4; ++ni) {
      const int r = wn * 64 + ni * 16 + l15;
      bfr[ni] = *(const half8*)&Bs[p][r * 32 + ((kq ^ (r & 3)) << 3)];
    }
#pragma unroll
    for (int mi = 0; mi < 4; ++mi)
#pragma unroll
      for (int ni = 0; ni < 4; ++ni)
        acc[mi][ni] = __builtin_amdgcn_mfma_f32_16x16x32_f16(a[mi], bfr[ni], acc[mi][ni], 0, 0, 0);
    __builtin_amdgcn_sched_barrier(0);
    __builtin_amdgcn_s_barrier();
    __builtin_amdgcn_sched_barrier(0);
  }

#pragma unroll
  for (int mi = 0; mi < 4; ++mi)
#pragma unroll
    for (int ni = 0; ni < 4; ++ni) {
      const size_t col = col0 + wn * 64 + ni * 16 + l15;
      const float bv = bias[col];
#pragma unroll
      for (int ri = 0; ri < 4; ++ri) {
        const size_t row = row0 + wm * 64 + mi * 16 + kq * 4 + ri;
        float v = acc[mi][ni][ri] + bv;
        C[row * N + col] = (h16)fmaxf(v, 0.f);
      }
    }
}

// ---- 64x128-tile single-buffered GEMM for T2 (R17).
template <int GYL>
__global__ __launch_bounds__(256, 4) void gemm_sb64(
    const h16* __restrict__ A, const h16* __restrict__ W,
    const float* __restrict__ bias, h16* __restrict__ C, int N, int K) {
  __shared__ __align__(16) h16 As[64 * 64];
  __shared__ __align__(16) h16 Bs[128 * 64];
  const int b = blockIdx.x;
  const int c8 = b & 7;
  const int q = b >> 3;
  const int jcol = q & ((1 << GYL) - 1);
  const int krow = ((q >> GYL) << 3) | c8;
  const int tid = threadIdx.x;
  const int lane = tid & 63;
  const int wave = tid >> 6;
  const int wm = wave >> 1, wn = wave & 1;
  const size_t row0 = (size_t)krow * 64;
  const size_t col0 = (size_t)jcol * 128;
  const int l15 = lane & 15;
  const int kq = lane >> 4;
  const int l7 = lane & 7;
  const int nt = K >> 6;

  const int srow = tid >> 3;
  const int sch = (tid & 7) ^ (srow & 7);
  const h16* ga = A + (row0 + srow) * (size_t)K + sch * 8;
  const h16* gb = W + (col0 + srow) * (size_t)K + sch * 8;

  f32x4 acc[2][4] = {};

  for (int t = 0; t < nt; ++t) {
    const int k0 = t << 6;
#pragma unroll
    for (int i = 0; i < 2; ++i)
      gload16(ga + (size_t)(i * 32) * K + k0, As + i * 2048 + tid * 8);
#pragma unroll
    for (int i = 0; i < 4; ++i)
      gload16(gb + (size_t)(i * 32) * K + k0, Bs + i * 2048 + tid * 8);
    __syncthreads();
#pragma unroll
    for (int kk = 0; kk < 2; ++kk) {
      const int kb = kk * 4 + kq;
      const int sl = (kb ^ l7) << 3;
      half8 a[2], bfr[4];
#pragma unroll
      for (int mi = 0; mi < 2; ++mi)
        a[mi] = *(const half8*)&As[(wm * 32 + mi * 16 + l15) * 64 + sl];
#pragma unroll
      for (int ni = 0; ni < 4; ++ni)
        bfr[ni] = *(const half8*)&Bs[(wn * 64 + ni * 16 + l15) * 64 + sl];
#pragma unroll
      for (int mi = 0; mi < 2; ++mi)
#pragma unroll
        for (int ni = 0; ni < 4; ++ni)
          acc[mi][ni] = __builtin_amdgcn_mfma_f32_16x16x32_f16(a[mi], bfr[ni], acc[mi][ni], 0, 0, 0);
    }
    __syncthreads();
  }

#pragma unroll
  for (int mi = 0; mi < 2; ++mi)
#pragma unroll
    for (int ni = 0; ni < 4; ++ni) {
      const size_t col = col0 + wn * 64 + ni * 16 + l15;
      const float bv = bias[col];
#pragma unroll
      for (int ri = 0; ri < 4; ++ri) {
        const size_t row = row0 + wm * 32 + mi * 16 + kq * 4 + ri;
        float v = acc[mi][ni][ri] + bv;
        C[row * N + col] = (h16)fmaxf(v, 0.f);
      }
    }
}

// ---- T3+top4+sigmoid fused, 32-row blocks (R15).
__global__ __launch_bounds__(256, 4) void gemm_t3s(
    const h16* __restrict__ A, const h16* __restrict__ W,
    const float* __restrict__ bias, const float* __restrict__ w4,
    const float* __restrict__ b4, float* __restrict__ out) {
  const int K = 512;
  __shared__ __align__(16) h16 As[32 * 64];
  __shared__ __align__(16) h16 Bs[256 * 64];
  __shared__ float red[4][32];
  const int tid = threadIdx.x;
  const int lane = tid & 63;
  const int w = tid >> 6;
  const int l15 = lane & 15;
  const int kq = lane >> 4;
  const int l7 = lane & 7;
  const size_t row0 = (size_t)blockIdx.x * 32;

  const int srow = tid >> 3;
  const int sch = (tid & 7) ^ (srow & 7);
  const h16* gA = A + (row0 + srow) * (size_t)K + sch * 8;
  const h16* gB = W + (size_t)srow * K + sch * 8;

  f32x4 acc[2][4] = {};
  for (int t = 0; t < 8; ++t) {
    const int k0 = t * 64;
    gload16(gA + k0, As + tid * 8);
#pragma unroll
    for (int i = 0; i < 8; ++i)
      gload16(gB + (size_t)(i * 32) * K + k0, Bs + i * 2048 + tid * 8);
    __syncthreads();
#pragma unroll
    for (int kk = 0; kk < 2; ++kk) {
      const int kb = kk * 4 + kq;
      const int sl = (kb ^ l7) << 3;
      half8 a[2], bfr[4];
#pragma unroll
      for (int mi = 0; mi < 2; ++mi)
        a[mi] = *(const half8*)&As[(mi * 16 + l15) * 64 + sl];
#pragma unroll
      for (int ni = 0; ni < 4; ++ni)
        bfr[ni] = *(const half8*)&Bs[(w * 64 + ni * 16 + l15) * 64 + sl];
#pragma unroll
      for (int mi = 0; mi < 2; ++mi)
#pragma unroll
        for (int ni = 0; ni < 4; ++ni)
          acc[mi][ni] = __builtin_amdgcn_mfma_f32_16x16x32_f16(a[mi], bfr[ni], acc[mi][ni], 0, 0, 0);
    }
    __syncthreads();
  }

#pragma unroll
  for (int mi = 0; mi < 2; ++mi) {
    float s[4] = {0.f, 0.f, 0.f, 0.f};
#pragma unroll
    for (int ni = 0; ni < 4; ++ni) {
      const int col = w * 64 + ni * 16 + l15;
      const float bv = bias[col];
      const float wv = w4[col];
#pragma unroll
      for (int ri = 0; ri < 4; ++ri)
        s[ri] += fmaxf(acc[mi][ni][ri] + bv, 0.f) * wv;
    }
#pragma unroll
    for (int ri = 0; ri < 4; ++ri) {
      float v = s[ri];
      v += __shfl_xor(v, 1);
      v += __shfl_xor(v, 2);
      v += __shfl_xor(v, 4);
      v += __shfl_xor(v, 8);
      if (l15 == 0) red[w][mi * 16 + kq * 4 + ri] = v;
    }
  }
  __syncthreads();
  if (tid < 32) {
    float v = red[0][tid] + red[1][tid] + red[2][tid] + red[3][tid] + b4[0];
    out[row0 + tid] = 1.f / (1.f + expf(-v));
  }
}

// ---- fused embedding gather + interaction (R15).
__global__ __launch_bounds__(256) void interact_k(
    const h16* __restrict__ X, const float* __restrict__ emb,
    const int* __restrict__ lSi, h16* __restrict__ z) {
  __shared__ __align__(16) h16 T[4][32][136];
  const int lane = threadIdx.x & 63;
  const int wv = threadIdx.x >> 6;
  const size_t b = (size_t)blockIdx.x * 4 + wv;

  int idxs[NTAB];
#pragma unroll
  for (int t = 0; t < NTAB; ++t) idxs[t] = lSi[t * NB + (int)b];

  for (int i = lane; i < 5 * 128; i += 64)
    T[wv][27 + (i >> 7)][i & 127] = (h16)0.f;

  {
    half2v v = *(const half2v*)(X + b * 128 + lane * 2);
    *(half2v*)&T[wv][0][lane * 2] = v;
    *(half2v*)(z + b * 512 + lane * 2) = v;
  }
  const int thalf = lane >> 5;
  const int c4 = (lane & 31) * 4;
#pragma unroll
  for (int i = 0; i < NTAB / 2; ++i) {
    const int t = 2 * i + thalf;
    const f32x4 v = *(const f32x4*)(emb + ((size_t)t * NR + idxs[t]) * 128 + c4);
    half4 h;
#pragma unroll
    for (int j = 0; j < 4; ++j) h[j] = (h16)v[j];
    *(half4*)&T[wv][1 + t][c4] = h;
  }

  __syncthreads();

  f32x4 acc00 = {}, acc10 = {}, acc11 = {};
  const int l15 = lane & 15;
  const int kq = lane >> 4;
#pragma unroll
  for (int kk = 0; kk < 4; ++kk) {
    const int ko = kk * 32 + kq * 8;
    half8 a0 = *(const half8*)&T[wv][l15][ko];
    half8 a1 = *(const half8*)&T[wv][16 + l15][ko];
    acc00 = __builtin_amdgcn_mfma_f32_16x16x32_f16(a0, a0, acc00, 0, 0, 0);
    acc10 = __builtin_amdgcn_mfma_f32_16x16x32_f16(a1, a0, acc10, 0, 0, 0);
    acc11 = __builtin_amdgcn_mfma_f32_16x16x32_f16(a1, a1, acc11, 0, 0, 0);
  }
  h16* zr = z + b * 512 + 128;
#pragma unroll
  for (int ri = 0; ri < 4; ++ri) {
    int i0 = kq * 4 + ri;
    int i1 = 16 + i0;
    if (l15 < i0) zr[i0 * (i0 - 1) / 2 + l15] = (h16)acc00[ri];
    if (i1 < 27) {
      zr[i1 * (i1 - 1) / 2 + l15] = (h16)acc10[ri];
      int j1 = 16 + l15;
      if (j1 < i1) zr[i1 * (i1 - 1) / 2 + j1] = (h16)acc11[ri];
    }
  }
}

extern "C" void kernel_launch(void* const* d_in, const int* in_sizes, int n_in,
                              void* d_out, int out_size, void* d_ws, size_t ws_size,
                              hipStream_t stream) {
  const float* dense_x = (const float*)d_in[0];
  const int* lSi = (const int*)d_in[2];
  const float* emb = (const float*)d_in[3];
  const float* bw0 = (const float*)d_in[4];
  const float* bb0 = (const float*)d_in[5];
  const float* bw1 = (const float*)d_in[6];
  const float* bb1 = (const float*)d_in[7];
  const float* bw2 = (const float*)d_in[8];
  const float* bb2 = (const float*)d_in[9];
  const float* tw0 = (const float*)d_in[10];
  const float* tb0 = (const float*)d_in[11];
  const float* tw1 = (const float*)d_in[12];
  const float* tb1 = (const float*)d_in[13];
  const float* tw2 = (const float*)d_in[14];
  const float* tb2 = (const float*)d_in[15];
  const float* tw3 = (const float*)d_in[16];
  const float* tb3 = (const float*)d_in[17];
  const float* tw4 = (const float*)d_in[18];
  const float* tb4 = (const float*)d_in[19];
  float* out = (float*)d_out;

  char* ws = (char*)d_ws;
  const size_t MB = (size_t)1 << 20;
  h16* Xc = (h16*)(ws + 24 * MB);
  h16* Zz = (h16*)(ws + 32 * MB);
  h16* U0 = (h16*)(ws + 48 * MB);
  h16* U1 = (h16*)(ws + 0 * MB);
  h16* U2 = (h16*)(ws + 32 * MB);
  h16* w1p = (h16*)(ws + 80 * MB);
  h16* w2p = w1p + 256 * 512;
  h16* t0p = w2p + 128 * 256;
  h16* t1p = t0p + 1024 * 512;
  h16* t2p = t1p + 1024 * 1024;
  h16* t3p = t2p + 512 * 1024;
  h16* w0p = w1p + 2392064;
  (void)in_sizes; (void)n_in; (void)out_size; (void)ws_size;

  cvt_all_k<<<9344 + 64, 256, 0, stream>>>(bw1, bw2, tw0, tw1, tw2, tw3, bw0, w1p);
  mid_k<<<512, 256, 0, stream>>>(dense_x, w0p, bb0, w1p, bb1, w2p, bb2, Xc);
  interact_k<<<NB / 4, 256, 0, stream>>>(Xc, emb, lSi, Zz);
  gemm_sb<3><<<128 * 8, 256, 0, stream>>>(Zz, t0p, tb0, U0, 1024, 512);
  gemm_db32<3><<<128 * 8, 256, 0, stream>>>(U0, t1p, tb1, U1, 1024, 1024);
  gemm_sb64<2><<<256 * 4, 256, 0, stream>>>(U1, t2p, tb2, U2, 512, 1024);
  gemm_t3s<<<512, 256, 0, stream>>>(U2, t3p, tb3, tw4, tb4, out);
}

// Round 21
// 166.142 us; speedup vs baseline: 1.0555x; 1.0555x over previous
//
#include <hip/hip_runtime.h>
#include <cstdint>
#include <cstddef>

typedef _Float16 h16;
typedef __attribute__((ext_vector_type(8))) _Float16 half8;
typedef __attribute__((ext_vector_type(4))) _Float16 half4;
typedef __attribute__((ext_vector_type(2))) _Float16 half2v;
typedef __attribute__((ext_vector_type(4))) float f32x4;
typedef __attribute__((ext_vector_type(2))) float f32x2;

#define NB 16384
#define NTAB 26
#define NR 100000

__device__ __forceinline__ void gload16(const void* g, void* l) {
  __builtin_amdgcn_global_load_lds(
      (const __attribute__((address_space(1))) unsigned int*)g,
      (__attribute__((address_space(3))) unsigned int*)l, 16, 0, 0);
}

// ---- f32 -> fp16 weight conversion (7 segments, one launch).
// Last segment: W0 padded to [512][32] fp16 (K=13, zero pad) for mid_k's
// MFMA stage A.
__global__ __launch_bounds__(256) void cvt_all_k(
    const float* __restrict__ s0, const float* __restrict__ s1,
    const float* __restrict__ s2, const float* __restrict__ s3,
    const float* __restrict__ s4, const float* __restrict__ s5,
    const float* __restrict__ s6, h16* __restrict__ dst) {
  int b = blockIdx.x;
  const float* src; int K, kl, i0; size_t doff;
  if (b < 512)       { src=s0; K=512;  kl=9;  i0=(b-0)*256;    doff=0; }
  else if (b < 640)  { src=s1; K=256;  kl=8;  i0=(b-512)*256;  doff=131072; }
  else if (b < 2688) { src=s2; K=479;  kl=9;  i0=(b-640)*256;  doff=163840; }
  else if (b < 6784) { src=s3; K=1024; kl=10; i0=(b-2688)*256; doff=688128; }
  else if (b < 8832) { src=s4; K=1024; kl=10; i0=(b-6784)*256; doff=1736704; }
  else if (b < 9344) { src=s5; K=512;  kl=9;  i0=(b-8832)*256; doff=2260992; }
  else               { src=s6; K=13;   kl=5;  i0=(b-9344)*256; doff=2392064; }
  int i = i0 + threadIdx.x;
  int n = i >> kl, k = i & ((1 << kl) - 1);
  dst[doff + i] = (k < K) ? (h16)src[(size_t)n * K + k] : (h16)0.f;
}

// ---- fully fused bottom stack (R18 + MFMA stage A):
// Xc = relu(relu(relu(x@W0^T+b0)@W1^T+b1)@W2^T+b2), 32-row blocks, grid 512.
__global__ __launch_bounds__(256, 2) void mid_k(
    const float* __restrict__ x, const h16* __restrict__ W0p,
    const float* __restrict__ b0, const h16* __restrict__ W1,
    const float* __restrict__ b1, const h16* __restrict__ W2,
    const float* __restrict__ b2, h16* __restrict__ Xc) {
  __shared__ __align__(16) h16 Y0s[32 * 520];  // 33.3KB (Y1 overlays)
  __shared__ __align__(16) h16 Sb[256 * 64];   // 32KB
  __shared__ __align__(16) h16 xs16[32 * 32];  // 2KB
  h16* Y1 = Y0s;                               // [32][264] overlay
  const int tid = threadIdx.x;
  const int lane = tid & 63;
  const int w = tid >> 6;
  const int l15 = lane & 15;
  const int kq = lane >> 4;
  const int l7 = lane & 7;
  const size_t row0 = (size_t)blockIdx.x * 32;

  // --- stage A: bot0 via MFMA
  for (int i = tid; i < 32 * 32; i += 256) xs16[i] = (h16)0.f;
  __syncthreads();
  for (int i = tid; i < 32 * 13; i += 256) {
    int r = i / 13, k = i - r * 13;
    xs16[r * 32 + k] = (h16)x[(row0 + r) * 13 + k];
  }
  __syncthreads();
#pragma unroll
  for (int mi = 0; mi < 2; ++mi) {
    half8 xf = *(const half8*)&xs16[(mi * 16 + l15) * 32 + kq * 8];
#pragma unroll
    for (int ni = 0; ni < 8; ++ni) {
      const int c = w * 128 + ni * 16 + l15;
      half8 wf = *(const half8*)&W0p[c * 32 + kq * 8];
      f32x4 a0 = {};
      a0 = __builtin_amdgcn_mfma_f32_16x16x32_f16(wf, xf, a0, 0, 0, 0);
      const int colb = w * 128 + ni * 16 + kq * 4;
      const f32x4 bv = *(const f32x4*)&b0[colb];
      half4 h;
#pragma unroll
      for (int ri = 0; ri < 4; ++ri)
        h[ri] = (h16)fmaxf(a0[ri] + bv[ri], 0.f);
      *(half4*)&Y0s[(mi * 16 + l15) * 520 + colb] = h;
    }
  }
  __syncthreads();

  // --- stage B: L1 GEMM (K=512), A from Y0s (linear padded), B staged
  const int srow = tid >> 3;
  const int sch = (tid & 7) ^ (srow & 7);
  const h16* gB = W1 + (size_t)srow * 512 + sch * 8;

  f32x4 acc[2][4] = {};
  for (int t = 0; t < 8; ++t) {
    const int k0 = t * 64;
#pragma unroll
    for (int i = 0; i < 8; ++i)
      gload16(gB + (size_t)(i * 32) * 512 + k0, Sb + i * 2048 + tid * 8);
    __syncthreads();
#pragma unroll
    for (int kk = 0; kk < 2; ++kk) {
      const int kb = kk * 4 + kq;
      const int sl = (kb ^ l7) << 3;
      half8 a[2], bfr[4];
#pragma unroll
      for (int mi = 0; mi < 2; ++mi)
        a[mi] = *(const half8*)&Y0s[(mi * 16 + l15) * 520 + k0 + kb * 8];
#pragma unroll
      for (int ni = 0; ni < 4; ++ni)
        bfr[ni] = *(const half8*)&Sb[(w * 64 + ni * 16 + l15) * 64 + sl];
#pragma unroll
      for (int mi = 0; mi < 2; ++mi)
#pragma unroll
        for (int ni = 0; ni < 4; ++ni)
          acc[mi][ni] = __builtin_amdgcn_mfma_f32_16x16x32_f16(bfr[ni], a[mi], acc[mi][ni], 0, 0, 0);
    }
    __syncthreads();
  }

  // swapped-layout epilogue -> Y1 (overlay; all Y0s reads completed above)
#pragma unroll
  for (int mi = 0; mi < 2; ++mi) {
    const int row = mi * 16 + l15;
#pragma unroll
    for (int ni = 0; ni < 4; ++ni) {
      const int col = w * 64 + ni * 16 + kq * 4;
      const f32x4 bv = *(const f32x4*)&b1[col];
      half4 h;
#pragma unroll
      for (int ri = 0; ri < 4; ++ri)
        h[ri] = (h16)fmaxf(acc[mi][ni][ri] + bv[ri], 0.f);
      *(half4*)&Y1[row * 264 + col] = h;
    }
  }
  __syncthreads();

  // --- stage C: L2 GEMM (K=256), A from Y1, B direct from W2
  f32x4 acc2[2][2] = {};
  for (int ks = 0; ks < 8; ++ks) {
    half8 av[2], bv[2];
#pragma unroll
    for (int mi = 0; mi < 2; ++mi)
      av[mi] = *(const half8*)&Y1[(mi * 16 + l15) * 264 + ks * 32 + kq * 8];
#pragma unroll
    for (int nf = 0; nf < 2; ++nf) {
      const int col = (w * 2 + nf) * 16 + l15;
      bv[nf] = *(const half8*)&W2[(size_t)col * 256 + ks * 32 + kq * 8];
    }
#pragma unroll
    for (int mi = 0; mi < 2; ++mi)
#pragma unroll
      for (int nf = 0; nf < 2; ++nf)
        acc2[mi][nf] = __builtin_amdgcn_mfma_f32_16x16x32_f16(bv[nf], av[mi], acc2[mi][nf], 0, 0, 0);
  }
#pragma unroll
  for (int mi = 0; mi < 2; ++mi) {
    const size_t row = row0 + mi * 16 + l15;
#pragma unroll
    for (int nf = 0; nf < 2; ++nf) {
      const int col = (w * 2 + nf) * 16 + kq * 4;
      const f32x4 bv = *(const f32x4*)&b2[col];
      half4 h;
#pragma unroll
      for (int ri = 0; ri < 4; ++ri)
        h[ri] = (h16)fmaxf(acc2[mi][nf][ri] + bv[ri], 0.f);
      *(half4*)&Xc[row * 128 + col] = h;
    }
  }
}

// ---- 128x128-tile single-buffered fp16 MFMA GEMM (R15 best): T0/T1.
template <int GYL>
__global__ __launch_bounds__(256, 4) void gemm_sb(
    const h16* __restrict__ A, const h16* __restrict__ W,
    const float* __restrict__ bias, h16* __restrict__ C, int N, int K) {
  __shared__ __align__(16) h16 As[128 * 64];
  __shared__ __align__(16) h16 Bs[128 * 64];
  const int b = blockIdx.x;
  const int c8 = b & 7;
  const int q = b >> 3;
  const int jcol = q & ((1 << GYL) - 1);
  const int krow = ((q >> GYL) << 3) | c8;
  const int tid = threadIdx.x;
  const int lane = tid & 63;
  const int wave = tid >> 6;
  const int wm = wave >> 1, wn = wave & 1;
  const size_t row0 = (size_t)krow * 128;
  const size_t col0 = (size_t)jcol * 128;
  const int lr = lane >> 3;
  const int swzc = (((lane & 7) ^ lr) << 3);
  const int l15 = lane & 15;
  const int kq = lane >> 4;
  const int l7 = lane & 7;
  const int nt = K >> 6;

  const h16* ga = A + (row0 + wave * 32 + lr) * (size_t)K + swzc;
  const h16* gb = W + (col0 + wave * 32 + lr) * (size_t)K + swzc;

  f32x4 acc[4][4] = {};

  for (int t = 0; t < nt; ++t) {
    const int k0 = t << 6;
    h16* la = As + wave * 2048;
    h16* lb = Bs + wave * 2048;
#pragma unroll
    for (int i = 0; i < 4; ++i) {
      gload16(ga + (size_t)i * 8 * K + k0, la + i * 512);
      gload16(gb + (size_t)i * 8 * K + k0, lb + i * 512);
    }
    __syncthreads();
#pragma unroll
    for (int kk = 0; kk < 2; ++kk) {
      half8 a[4], bfr[4];
      const int kb = kk * 4 + kq;
#pragma unroll
      for (int mi = 0; mi < 4; ++mi)
        a[mi] = *(const half8*)&As[(wm * 64 + mi * 16 + l15) * 64 + ((kb ^ l7) << 3)];
#pragma unroll
      for (int ni = 0; ni < 4; ++ni)
        bfr[ni] = *(const half8*)&Bs[(wn * 64 + ni * 16 + l15) * 64 + ((kb ^ l7) << 3)];
#pragma unroll
      for (int mi = 0; mi < 4; ++mi)
#pragma unroll
        for (int ni = 0; ni < 4; ++ni)
          acc[mi][ni] = __builtin_amdgcn_mfma_f32_16x16x32_f16(a[mi], bfr[ni], acc[mi][ni], 0, 0, 0);
    }
    __syncthreads();
  }

#pragma unroll
  for (int mi = 0; mi < 4; ++mi)
#pragma unroll
    for (int ni = 0; ni < 4; ++ni) {
      const size_t col = col0 + wn * 64 + ni * 16 + l15;
      const float bv = bias[col];
#pragma unroll
      for (int ri = 0; ri < 4; ++ri) {
        const size_t row = row0 + wm * 64 + mi * 16 + kq * 4 + ri;
        float v = acc[mi][ni][ri] + bv;
        C[row * N + col] = (h16)fmaxf(v, 0.f);
      }
    }
}

// ---- 64x128-tile single-buffered GEMM for T2 (R17: 4 blocks/CU).
template <int GYL>
__global__ __launch_bounds__(256, 4) void gemm_sb64(
    const h16* __restrict__ A, const h16* __restrict__ W,
    const float* __restrict__ bias, h16* __restrict__ C, int N, int K) {
  __shared__ __align__(16) h16 As[64 * 64];
  __shared__ __align__(16) h16 Bs[128 * 64];
  const int b = blockIdx.x;
  const int c8 = b & 7;
  const int q = b >> 3;
  const int jcol = q & ((1 << GYL) - 1);
  const int krow = ((q >> GYL) << 3) | c8;
  const int tid = threadIdx.x;
  const int lane = tid & 63;
  const int wave = tid >> 6;
  const int wm = wave >> 1, wn = wave & 1;
  const size_t row0 = (size_t)krow * 64;
  const size_t col0 = (size_t)jcol * 128;
  const int l15 = lane & 15;
  const int kq = lane >> 4;
  const int l7 = lane & 7;
  const int nt = K >> 6;

  const int srow = tid >> 3;
  const int sch = (tid & 7) ^ (srow & 7);
  const h16* ga = A + (row0 + srow) * (size_t)K + sch * 8;
  const h16* gb = W + (col0 + srow) * (size_t)K + sch * 8;

  f32x4 acc[2][4] = {};

  for (int t = 0; t < nt; ++t) {
    const int k0 = t << 6;
#pragma unroll
    for (int i = 0; i < 2; ++i)
      gload16(ga + (size_t)(i * 32) * K + k0, As + i * 2048 + tid * 8);
#pragma unroll
    for (int i = 0; i < 4; ++i)
      gload16(gb + (size_t)(i * 32) * K + k0, Bs + i * 2048 + tid * 8);
    __syncthreads();
#pragma unroll
    for (int kk = 0; kk < 2; ++kk) {
      const int kb = kk * 4 + kq;
      const int sl = (kb ^ l7) << 3;
      half8 a[2], bfr[4];
#pragma unroll
      for (int mi = 0; mi < 2; ++mi)
        a[mi] = *(const half8*)&As[(wm * 32 + mi * 16 + l15) * 64 + sl];
#pragma unroll
      for (int ni = 0; ni < 4; ++ni)
        bfr[ni] = *(const half8*)&Bs[(wn * 64 + ni * 16 + l15) * 64 + sl];
#pragma unroll
      for (int mi = 0; mi < 2; ++mi)
#pragma unroll
        for (int ni = 0; ni < 4; ++ni)
          acc[mi][ni] = __builtin_amdgcn_mfma_f32_16x16x32_f16(a[mi], bfr[ni], acc[mi][ni], 0, 0, 0);
    }
    __syncthreads();
  }

#pragma unroll
  for (int mi = 0; mi < 2; ++mi)
#pragma unroll
    for (int ni = 0; ni < 4; ++ni) {
      const size_t col = col0 + wn * 64 + ni * 16 + l15;
      const float bv = bias[col];
#pragma unroll
      for (int ri = 0; ri < 4; ++ri) {
        const size_t row = row0 + wm * 32 + mi * 16 + kq * 4 + ri;
        float v = acc[mi][ni][ri] + bv;
        C[row * N + col] = (h16)fmaxf(v, 0.f);
      }
    }
}

// ---- T3+top4+sigmoid fused, 32-row blocks (R15).
__global__ __launch_bounds__(256, 4) void gemm_t3s(
    const h16* __restrict__ A, const h16* __restrict__ W,
    const float* __restrict__ bias, const float* __restrict__ w4,
    const float* __restrict__ b4, float* __restrict__ out) {
  const int K = 512;
  __shared__ __align__(16) h16 As[32 * 64];
  __shared__ __align__(16) h16 Bs[256 * 64];
  __shared__ float red[4][32];
  const int tid = threadIdx.x;
  const int lane = tid & 63;
  const int w = tid >> 6;
  const int l15 = lane & 15;
  const int kq = lane >> 4;
  const int l7 = lane & 7;
  const size_t row0 = (size_t)blockIdx.x * 32;

  const int srow = tid >> 3;
  const int sch = (tid & 7) ^ (srow & 7);
  const h16* gA = A + (row0 + srow) * (size_t)K + sch * 8;
  const h16* gB = W + (size_t)srow * K + sch * 8;

  f32x4 acc[2][4] = {};
  for (int t = 0; t < 8; ++t) {
    const int k0 = t * 64;
    gload16(gA + k0, As + tid * 8);
#pragma unroll
    for (int i = 0; i < 8; ++i)
      gload16(gB + (size_t)(i * 32) * K + k0, Bs + i * 2048 + tid * 8);
    __syncthreads();
#pragma unroll
    for (int kk = 0; kk < 2; ++kk) {
      const int kb = kk * 4 + kq;
      const int sl = (kb ^ l7) << 3;
      half8 a[2], bfr[4];
#pragma unroll
      for (int mi = 0; mi < 2; ++mi)
        a[mi] = *(const half8*)&As[(mi * 16 + l15) * 64 + sl];
#pragma unroll
      for (int ni = 0; ni < 4; ++ni)
        bfr[ni] = *(const half8*)&Bs[(w * 64 + ni * 16 + l15) * 64 + sl];
#pragma unroll
      for (int mi = 0; mi < 2; ++mi)
#pragma unroll
        for (int ni = 0; ni < 4; ++ni)
          acc[mi][ni] = __builtin_amdgcn_mfma_f32_16x16x32_f16(a[mi], bfr[ni], acc[mi][ni], 0, 0, 0);
    }
    __syncthreads();
  }

#pragma unroll
  for (int mi = 0; mi < 2; ++mi) {
    float s[4] = {0.f, 0.f, 0.f, 0.f};
#pragma unroll
    for (int ni = 0; ni < 4; ++ni) {
      const int col = w * 64 + ni * 16 + l15;
      const float bv = bias[col];
      const float wv = w4[col];
#pragma unroll
      for (int ri = 0; ri < 4; ++ri)
        s[ri] += fmaxf(acc[mi][ni][ri] + bv, 0.f) * wv;
    }
#pragma unroll
    for (int ri = 0; ri < 4; ++ri) {
      float v = s[ri];
      v += __shfl_xor(v, 1);
      v += __shfl_xor(v, 2);
      v += __shfl_xor(v, 4);
      v += __shfl_xor(v, 8);
      if (l15 == 0) red[w][mi * 16 + kq * 4 + ri] = v;
    }
  }
  __syncthreads();
  if (tid < 32) {
    float v = red[0][tid] + red[1][tid] + red[2][tid] + red[3][tid] + b4[0];
    out[row0 + tid] = 1.f / (1.f + expf(-v));
  }
}

// ---- fused embedding gather + interaction (R15).
__global__ __launch_bounds__(256) void interact_k(
    const h16* __restrict__ X, const float* __restrict__ emb,
    const int* __restrict__ lSi, h16* __restrict__ z) {
  __shared__ __align__(16) h16 T[4][32][136];
  const int lane = threadIdx.x & 63;
  const int wv = threadIdx.x >> 6;
  const size_t b = (size_t)blockIdx.x * 4 + wv;

  int idxs[NTAB];
#pragma unroll
  for (int t = 0; t < NTAB; ++t) idxs[t] = lSi[t * NB + (int)b];

  for (int i = lane; i < 5 * 128; i += 64)
    T[wv][27 + (i >> 7)][i & 127] = (h16)0.f;

  {
    half2v v = *(const half2v*)(X + b * 128 + lane * 2);
    *(half2v*)&T[wv][0][lane * 2] = v;
    *(half2v*)(z + b * 512 + lane * 2) = v;
  }
  const int thalf = lane >> 5;
  const int c4 = (lane & 31) * 4;
#pragma unroll
  for (int i = 0; i < NTAB / 2; ++i) {
    const int t = 2 * i + thalf;
    const f32x4 v = *(const f32x4*)(emb + ((size_t)t * NR + idxs[t]) * 128 + c4);
    half4 h;
#pragma unroll
    for (int j = 0; j < 4; ++j) h[j] = (h16)v[j];
    *(half4*)&T[wv][1 + t][c4] = h;
  }

  __syncthreads();

  f32x4 acc00 = {}, acc10 = {}, acc11 = {};
  const int l15 = lane & 15;
  const int kq = lane >> 4;
#pragma unroll
  for (int kk = 0; kk < 4; ++kk) {
    const int ko = kk * 32 + kq * 8;
    half8 a0 = *(const half8*)&T[wv][l15][ko];
    half8 a1 = *(const half8*)&T[wv][16 + l15][ko];
    acc00 = __builtin_amdgcn_mfma_f32_16x16x32_f16(a0, a0, acc00, 0, 0, 0);
    acc10 = __builtin_amdgcn_mfma_f32_16x16x32_f16(a1, a0, acc10, 0, 0, 0);
    acc11 = __builtin_amdgcn_mfma_f32_16x16x32_f16(a1, a1, acc11, 0, 0, 0);
  }
  h16* zr = z + b * 512 + 128;
#pragma unroll
  for (int ri = 0; ri < 4; ++ri) {
    int i0 = kq * 4 + ri;
    int i1 = 16 + i0;
    if (l15 < i0) zr[i0 * (i0 - 1) / 2 + l15] = (h16)acc00[ri];
    if (i1 < 27) {
      zr[i1 * (i1 - 1) / 2 + l15] = (h16)acc10[ri];
      int j1 = 16 + l15;
      if (j1 < i1) zr[i1 * (i1 - 1) / 2 + j1] = (h16)acc11[ri];
    }
  }
}

extern "C" void kernel_launch(void* const* d_in, const int* in_sizes, int n_in,
                              void* d_out, int out_size, void* d_ws, size_t ws_size,
                              hipStream_t stream) {
  const float* dense_x = (const float*)d_in[0];
  const int* lSi = (const int*)d_in[2];
  const float* emb = (const float*)d_in[3];
  const float* bw0 = (const float*)d_in[4];
  const float* bb0 = (const float*)d_in[5];
  const float* bw1 = (const float*)d_in[6];
  const float* bb1 = (const float*)d_in[7];
  const float* bw2 = (const float*)d_in[8];
  const float* bb2 = (const float*)d_in[9];
  const float* tw0 = (const float*)d_in[10];
  const float* tb0 = (const float*)d_in[11];
  const float* tw1 = (const float*)d_in[12];
  const float* tb1 = (const float*)d_in[13];
  const float* tw2 = (const float*)d_in[14];
  const float* tb2 = (const float*)d_in[15];
  const float* tw3 = (const float*)d_in[16];
  const float* tb3 = (const float*)d_in[17];
  const float* tw4 = (const float*)d_in[18];
  const float* tb4 = (const float*)d_in[19];
  float* out = (float*)d_out;

  char* ws = (char*)d_ws;
  const size_t MB = (size_t)1 << 20;
  h16* Xc = (h16*)(ws + 24 * MB);   // [B,128]    4MB   (dead after interact)
  h16* Zz = (h16*)(ws + 32 * MB);   // [B,512]   16MB   (dead after T0)
  h16* U0 = (h16*)(ws + 48 * MB);   // [B,1024]  32MB   (dead after T1)
  h16* U1 = (h16*)(ws + 0 * MB);    // [B,1024]  32MB
  h16* U2 = (h16*)(ws + 32 * MB);   // [B,512]   16MB   reuses Zz
  h16* w1p = (h16*)(ws + 80 * MB);  // fp16 weights, contiguous segments
  h16* w2p = w1p + 256 * 512;
  h16* t0p = w2p + 128 * 256;
  h16* t1p = t0p + 1024 * 512;
  h16* t2p = t1p + 1024 * 1024;
  h16* t3p = t2p + 512 * 1024;
  h16* w0p = w1p + 2392064;         // [512][32] fp16, K=13 zero-padded
  (void)in_sizes; (void)n_in; (void)out_size; (void)ws_size;

  cvt_all_k<<<9344 + 64, 256, 0, stream>>>(bw1, bw2, tw0, tw1, tw2, tw3, bw0, w1p);
  mid_k<<<512, 256, 0, stream>>>(dense_x, w0p, bb0, w1p, bb1, w2p, bb2, Xc);
  interact_k<<<NB / 4, 256, 0, stream>>>(Xc, emb, lSi, Zz);
  gemm_sb<3><<<128 * 8, 256, 0, stream>>>(Zz, t0p, tb0, U0, 1024, 512);
  gemm_sb<3><<<128 * 8, 256, 0, stream>>>(U0, t1p, tb1, U1, 1024, 1024);
  gemm_sb64<2><<<256 * 4, 256, 0, stream>>>(U1, t2p, tb2, U2, 512, 1024);
  gemm_t3s<<<512, 256, 0, stream>>>(U2, t3p, tb3, tw4, tb4, out);
}